// Round 7
// baseline (214.367 us; speedup 1.0000x reference)
//
#include <hip/hip_runtime.h>

// Embedding: out[t, :] = W[:, x[t]] + b   (W [256,100000] row-major f32)
//
// Round 7: two-phase, zero atomics. A/B test on the write-granule theory.
//  Phase T: WT[v][e] = W[e][v] + b[e].  Grid (391 vocab-bins x 4 e-groups).
//    - reads: r6-proven staging, 1 KB contiguous per W-row-visit.
//    - writes: per v a 256 B e-chunk, thread-contiguous 64 B pieces, PLAIN
//      stores (L2 write-combines). If this phase runs ~35 us writes are fine;
//      ~60 us means 256B-granule writes are the wall.
//  Phase C: out[t][:] = WT[x[t]][:]  (r3-proven 28 us: random 1KB reads of
//    L3-warm WT + sequential 1KB NT writes).
// Evidence r4 vs r6: k2 = 60 us for 64B AND 1KB read granules -> read granule
// was never the wall; suspicion moves to the scattered-write side.

#define VOCAB 100000
#define EMBED 256
#define NTOK  (32 * 2048)
#define TILEC 256                              // vocab cols per bin
#define NBIN  ((VOCAB + TILEC - 1) / TILEC)    // 391 (last bin 160 cols)
#define LSTRIDE 257                            // LDS row stride (odd)
#define WT_BYTES ((size_t)VOCAB * EMBED * 4)   // 102.4 MB

// ---- Phase T: transpose + bias ----
__global__ __launch_bounds__(256) void t_transpose(
    const float* __restrict__ W,
    const float* __restrict__ bias,
    float* __restrict__ WT)
{
    __shared__ float tileT[64 * LSTRIDE];      // [e_local][c]

    const int bin  = blockIdx.x;
    const int g    = blockIdx.y;               // e rows g*64 .. g*64+63
    const int v0   = bin * TILEC;
    const int cols = (VOCAB - v0 < TILEC) ? (VOCAB - v0) : TILEC;
    const int t    = threadIdx.x;
    const int lane = t & 63;
    const int wave = t >> 6;

    // stage 64 e-rows x cols: one wave covers a full row per pass,
    // 64 lanes x 16 B = 1 KB contiguous per row-visit.
    #pragma unroll
    for (int j = 0; j < 16; ++j) {
        const int r  = j * 4 + wave;           // e_local 0..63
        const int c4 = lane << 2;
        if (c4 < cols) {
            const float4 w = *reinterpret_cast<const float4*>(
                W + (size_t)(g * 64 + r) * VOCAB + v0 + c4);
            tileT[r * LSTRIDE + c4 + 0] = w.x;
            tileT[r * LSTRIDE + c4 + 1] = w.y;
            tileT[r * LSTRIDE + c4 + 2] = w.z;
            tileT[r * LSTRIDE + c4 + 3] = w.w;
        }
    }

    const float4 bv = *reinterpret_cast<const float4*>(bias + g * 64 + (t & 15) * 4);
    // note: we need bias at e = fq*16 + 4m below; load per-thread slice instead:
    __syncthreads();

    // write out: per pass 64 c-values; thread -> (c = p*64 + t>>2, fq = t&3),
    // writes 4 float4 covering e_local fq*16 .. fq*16+15 (contiguous 64 B/thread).
    const int fq = t & 3;
    float b0[16];
    #pragma unroll
    for (int m = 0; m < 16; ++m) b0[m] = bias[g * 64 + fq * 16 + m];

    #pragma unroll
    for (int p = 0; p < 4; ++p) {
        const int c = p * 64 + (t >> 2);
        if (c < cols) {
            float* dst = WT + (size_t)(v0 + c) * EMBED + g * 64 + fq * 16;
            #pragma unroll
            for (int m = 0; m < 4; ++m) {
                float4 r;
                r.x = tileT[(fq * 16 + 4 * m + 0) * LSTRIDE + c] + b0[4 * m + 0];
                r.y = tileT[(fq * 16 + 4 * m + 1) * LSTRIDE + c] + b0[4 * m + 1];
                r.z = tileT[(fq * 16 + 4 * m + 2) * LSTRIDE + c] + b0[4 * m + 2];
                r.w = tileT[(fq * 16 + 4 * m + 3) * LSTRIDE + c] + b0[4 * m + 3];
                *reinterpret_cast<float4*>(dst + 4 * m) = r;   // plain store: L2 combines
            }
        }
    }
    (void)bv;
}

// ---- Phase C: row copy (r3-proven) ----
__global__ __launch_bounds__(256) void c_copy(
    const int* __restrict__ x,
    const float* __restrict__ WT,
    float* __restrict__ out)
{
    const int tid   = blockIdx.x * blockDim.x + threadIdx.x;
    const int token = tid >> 6;
    const int e     = (tid & 63) << 2;
    if (token >= NTOK) return;

    const int v = x[token];    // wave-uniform
    const float4 r = *reinterpret_cast<const float4*>(WT + (size_t)v * EMBED + e);
    __builtin_nontemporal_store(r.x, out + (size_t)token * EMBED + e + 0);
    __builtin_nontemporal_store(r.y, out + (size_t)token * EMBED + e + 1);
    __builtin_nontemporal_store(r.z, out + (size_t)token * EMBED + e + 2);
    __builtin_nontemporal_store(r.w, out + (size_t)token * EMBED + e + 3);
}

// fallback: direct column gather, if ws too small
__global__ __launch_bounds__(256) void embed_gather_direct(
    const int* __restrict__ x,
    const float* __restrict__ W,
    const float* __restrict__ bias,
    float* __restrict__ out)
{
    const int tid   = blockIdx.x * blockDim.x + threadIdx.x;
    const int token = tid >> 6;
    const int e     = (tid & 63) << 2;
    if (token >= NTOK) return;
    const int v = x[token];
    const float4 bv = *reinterpret_cast<const float4*>(bias + e);
    float4 r;
    r.x = W[(size_t)(e + 0) * VOCAB + v] + bv.x;
    r.y = W[(size_t)(e + 1) * VOCAB + v] + bv.y;
    r.z = W[(size_t)(e + 2) * VOCAB + v] + bv.z;
    r.w = W[(size_t)(e + 3) * VOCAB + v] + bv.w;
    *reinterpret_cast<float4*>(out + (size_t)token * EMBED + e) = r;
}

extern "C" void kernel_launch(void* const* d_in, const int* in_sizes, int n_in,
                              void* d_out, int out_size, void* d_ws, size_t ws_size,
                              hipStream_t stream)
{
    const int*   x = (const int*)d_in[0];
    const float* W = (const float*)d_in[1];
    const float* b = (const float*)d_in[2];
    float*     out = (float*)d_out;

    if (ws_size >= WT_BYTES) {
        float* WT = (float*)d_ws;
        dim3 tg(NBIN, 4);
        t_transpose<<<tg, 256, 0, stream>>>(W, b, WT);
        c_copy<<<NTOK * 64 / 256, 256, 0, stream>>>(x, WT, out);
    } else {
        embed_gather_direct<<<NTOK * 64 / 256, 256, 0, stream>>>(x, W, b, out);
    }
}

// Round 8
// 188.858 us; speedup vs baseline: 1.1351x; 1.1351x over previous
//
#include <hip/hip_runtime.h>

// Embedding: out[t, :] = W[:, x[t]] + b   (W [256,100000] row-major f32)
//
// Round 8 = round-4 structure (best: 190.1us) with ONE mechanism change in k2:
// PLAIN stores instead of nontemporal. Evidence r2-r7: cold-W kernels stall at
// ~3 TB/s for every read granule (64B/128B/1KB) and occupancy (16%..76%);
// write-only fill = 6.7 TB/s; L3-warm-read + write = 4.6 TB/s. Last untested
// variable in the fast structure: NT scattered stores (bypass L2, uncombined
// at the MC) vs plain stores (L2 write-back aggregation).
// Trims: hipMemsetAsync replaces k0; k1 reads x as int4; CAP 256->64 with
// slist LDS prefetch; LSTRIDE 260 -> scatter reads are aligned ds_read_b128
// (r4's 800K conflict cycles were 8-way b32 scatter reads).

#define VOCAB 100000
#define EMBED 256
#define NTOK  (32 * 2048)
#define TILEW 16                  // vocab cols per bin = one 64B line
#define NTILE (VOCAB / TILEW)     // 6250 bins
#define CAP   64                  // slots per bin (Poisson mean 10.5; P(>64)~0)
#define LSTRIDE 260               // floats; 260*4=1040 (16B-aligned rows, b128-able)

// workspace ints: cnt [0,8192) | list [8192, 8192+NTILE*CAP) | flags [NTOK)
#define WS_CNT_OFF   0
#define WS_LIST_OFF  8192
#define WS_FLAG_OFF  (WS_LIST_OFF + NTILE * CAP)
#define WS_INTS      (WS_FLAG_OFF + NTOK)

__global__ __launch_bounds__(256) void k1_bucket(
    const int* __restrict__ x,
    int* __restrict__ cnt,
    int* __restrict__ list,
    int* __restrict__ flags)
{
    int t4 = (blockIdx.x * 256 + threadIdx.x) * 4;
    if (t4 >= NTOK) return;
    const int4 v4 = *reinterpret_cast<const int4*>(x + t4);
    #pragma unroll
    for (int j = 0; j < 4; ++j) {
        const int v   = (&v4.x)[j];
        const int t   = t4 + j;
        const int bin = v >> 4;
        const int i   = v & 15;
        const int pos = atomicAdd(&cnt[bin], 1);
        const int ovf = (pos >= CAP);
        if (!ovf) list[bin * CAP + pos] = t | (i << 16);
        flags[t] = ovf;            // written for ALL t (ws is poisoned)
    }
}

__global__ __launch_bounds__(256) void k2_scatter(
    const float* __restrict__ W,
    const float* __restrict__ bias,
    const int* __restrict__ cnt,
    const int* __restrict__ list,
    float* __restrict__ out)
{
    __shared__ float tileT[TILEW * LSTRIDE];   // [i][e]
    __shared__ int   slist[CAP];

    const int bin = blockIdx.x;
    const int v0  = bin << 4;
    const int t   = threadIdx.x;

    if (t < CAP) slist[t] = list[bin * CAP + t];   // 256B contiguous prefetch

    // stage 16x256 tile transposed: 4 float4/thread, each 64B line read once.
    // staging-store banks: (4*(i4+k)+e)%32 with 4*i4%32 in {0,16} -> 2-way = free.
    #pragma unroll
    for (int j = 0; j < 4; ++j) {
        const int e  = j * 64 + (t >> 2);
        const int i4 = (t & 3) << 2;
        const float4 w = *reinterpret_cast<const float4*>(
            W + (size_t)e * VOCAB + v0 + i4);
        tileT[(i4 + 0) * LSTRIDE + e] = w.x;
        tileT[(i4 + 1) * LSTRIDE + e] = w.y;
        tileT[(i4 + 2) * LSTRIDE + e] = w.z;
        tileT[(i4 + 3) * LSTRIDE + e] = w.w;
    }
    __syncthreads();

    int n = cnt[bin];                // wave-uniform scalar load
    if (n > CAP) n = CAP;

    const int wave = t >> 6;
    const int lane = t & 63;
    const float4 bv = *reinterpret_cast<const float4*>(bias + lane * 4);

    for (int k = wave; k < n; k += 4) {
        const int packed = slist[k];
        const int tok = packed & 0xFFFF;
        const int i   = packed >> 16;
        // aligned 16B LDS read (row start i*1040, lane offset 16B) -> ds_read_b128
        const float4 s = *reinterpret_cast<const float4*>(
            &tileT[i * LSTRIDE + lane * 4]);
        float4 r;
        r.x = s.x + bv.x;  r.y = s.y + bv.y;
        r.z = s.z + bv.z;  r.w = s.w + bv.w;
        // THE A/B: plain store (L2 write-back aggregation) instead of NT
        *reinterpret_cast<float4*>(out + (size_t)tok * EMBED + lane * 4) = r;
    }
}

__global__ __launch_bounds__(256) void k3_cleanup(
    const int* __restrict__ x,
    const float* __restrict__ W,
    const float* __restrict__ bias,
    const int* __restrict__ flags,
    float* __restrict__ out)
{
    int t = blockIdx.x * 256 + threadIdx.x;
    if (t >= NTOK) return;
    if (!flags[t]) return;              // never taken for this input
    int v = x[t];
    for (int e = 0; e < EMBED; ++e)
        out[(size_t)t * EMBED + e] = W[(size_t)e * VOCAB + v] + bias[e];
}

// fallback: direct column gather, if ws too small
__global__ __launch_bounds__(256) void embed_gather_direct(
    const int* __restrict__ x,
    const float* __restrict__ W,
    const float* __restrict__ bias,
    float* __restrict__ out)
{
    const int tid   = blockIdx.x * blockDim.x + threadIdx.x;
    const int token = tid >> 6;
    const int e     = (tid & 63) << 2;
    if (token >= NTOK) return;
    const int v = x[token];
    const float4 bv = *reinterpret_cast<const float4*>(bias + e);
    float4 r;
    r.x = W[(size_t)(e + 0) * VOCAB + v] + bv.x;
    r.y = W[(size_t)(e + 1) * VOCAB + v] + bv.y;
    r.z = W[(size_t)(e + 2) * VOCAB + v] + bv.z;
    r.w = W[(size_t)(e + 3) * VOCAB + v] + bv.w;
    *reinterpret_cast<float4*>(out + (size_t)token * EMBED + e) = r;
}

extern "C" void kernel_launch(void* const* d_in, const int* in_sizes, int n_in,
                              void* d_out, int out_size, void* d_ws, size_t ws_size,
                              hipStream_t stream)
{
    const int*   x = (const int*)d_in[0];
    const float* W = (const float*)d_in[1];
    const float* b = (const float*)d_in[2];
    float*     out = (float*)d_out;

    if (ws_size >= (size_t)WS_INTS * sizeof(int)) {
        int* ws    = (int*)d_ws;
        int* cnt   = ws + WS_CNT_OFF;
        int* list  = ws + WS_LIST_OFF;
        int* flags = ws + WS_FLAG_OFF;

        hipMemsetAsync(cnt, 0, NTILE * sizeof(int), stream);   // replaces k0
        k1_bucket <<<NTOK / 4 / 256, 256, 0, stream>>>(x, cnt, list, flags);
        k2_scatter<<<NTILE,          256, 0, stream>>>(W, b, cnt, list, out);
        k3_cleanup<<<NTOK / 256,     256, 0, stream>>>(x, W, b, flags, out);
    } else {
        embed_gather_direct<<<NTOK * 64 / 256, 256, 0, stream>>>(x, W, b, out);
    }
}